// Round 14
// baseline (332.602 us; speedup 1.0000x reference)
//
#include <hip/hip_runtime.h>
#include <cstdint>
#include <cstddef>

#define B_ 8
#define C_ 64
#define N_ 4096
#define O_ 64
#define ROWS_ (B_*N_)          // 32768
#define NSPLIT_ 2              // candidate splits per row in k_knn
#define CAPB_ 33               // per-lane LDS candidate cap (odd u64 stride: 2-way, free)
#define TAU_TILES_ 8           // tiles scanned for the tau upper bound
#define MIDROWS_ 16            // rows per k_mid block (TLP: 2048 blocks)
#define FINROWS_ 32            // rows per k_final block (TLP: 1024 blocks)

typedef unsigned long long u64;
typedef unsigned int u32;
typedef unsigned short u16;
typedef __attribute__((ext_vector_type(8))) short bf16x8;   // 8 bf16 = 4 VGPR
typedef __attribute__((ext_vector_type(16))) float f32x16;  // MFMA 32x32 acc

#define MFMA32(A,Bv,Cv) __builtin_amdgcn_mfma_f32_32x32x16_bf16(A,Bv,Cv,0,0,0)

// ---- workspace layout (bytes), total 35,782,656 ----
// xf   [ROWS][64] f32 : 0           (8 MB)   alive: transpose -> mid
// sq   [ROWS]     f32 : 8388608     (128 KB) alive: transpose -> knn
// kd   [ROWS][2][16] u32 : 8519680  (4 MB)   alive: knn -> mid
// ki   [ROWS][2][16] u16 : 16908288 (2 MB)   alive: knn -> mid
// pack [B][128][12][64][8] bf16 : 21102592 (12 MB) alive: transpose -> knn
// -- aliases (dead regions reused): --
// h1   [ROWS][64] f32 : 21102592 (over pack head, dead after knn; mid -> final)
// bn   acc[128]       : 33685504 (own region; zeroed by k_knn block 0)
#define OFF_XF   0
#define OFF_SQ   8388608
#define OFF_KD   8519680
#define OFF_KI   16908288
#define OFF_PACK 21102592
#define OFF_H1   21102592
#define OFF_BN   33685504

__device__ __forceinline__ void insert16(u64 kv[16], u64 key) {
  if (key < kv[15]) {
#pragma unroll
    for (int j = 15; j > 0; --j) {
      u64 a = kv[j-1], b = kv[j];
      kv[j] = (key < a) ? a : ((key < b) ? key : b);
    }
    kv[0] = (key < kv[0]) ? key : kv[0];
  }
}

// ---------------- K1: transpose [B,C,N] -> xf[B,N,C], sq, and bf16 split-pack ----
// 1024 blocks (4/CU): 32-n tiles; each block emits exactly one pack tile.
__global__ __launch_bounds__(256) void k_transpose(const float* __restrict__ x,
                                                   float* __restrict__ xf,
                                                   float* __restrict__ sq,
                                                   u16* __restrict__ pack) {
  __shared__ float lds[64 * 33];           // 64 c x 32 n, pad 33
  const int b  = blockIdx.x >> 7;          // 8 batches
  const int nt = blockIdx.x & 127;         // 128 n-tiles of 32
  const int n0 = nt << 5;
  const int tid = threadIdx.x;
  const float* xb = x + (size_t)b * C_ * N_;
  {
    const int nn = tid & 31;
    const int c0 = tid >> 5;               // 0..7
#pragma unroll
    for (int i = 0; i < 8; ++i) {
      int c = c0 + i * 8;
      lds[c * 33 + nn] = xb[(size_t)c * N_ + n0 + nn];   // 128B segments over n
    }
  }
  __syncthreads();
  {
    const int cc  = tid & 63;
    const int nn0 = tid >> 6;              // 0..3
#pragma unroll
    for (int i = 0; i < 8; ++i) {
      int nn = nn0 + i * 4;
      xf[((size_t)(b * N_ + n0 + nn)) * 64 + cc] = lds[cc * 33 + nn]; // coalesced over c
    }
  }
  if (tid < 32) {
    float s = 0.f;
#pragma unroll
    for (int c = 0; c < 64; ++c) { float v = lds[c * 33 + tid]; s += v * v; }
    sq[b * N_ + n0 + tid] = s;
  }
  {
    const int lane = tid & 63;
    const int slice = tid >> 6;                  // 4 k-slices of 16
    const int kb = slice * 16 + (lane >> 5) * 8;
    const int nl = lane & 31;
    bf16x8 H, M, L;
#pragma unroll
    for (int j = 0; j < 8; ++j) {
      float f = lds[(kb + j) * 33 + nl];
      u32 u = __float_as_uint(f);
      u32 rh = (u + 0x7FFFu + ((u >> 16) & 1u)) >> 16;   // RNE to bf16
      float bh = __uint_as_float(rh << 16);
      float f1 = f - bh;                                  // exact (Sterbenz)
      u = __float_as_uint(f1);
      u32 rm = (u + 0x7FFFu + ((u >> 16) & 1u)) >> 16;
      float bm = __uint_as_float(rm << 16);
      float f2 = f1 - bm;                                 // exact
      u = __float_as_uint(f2);
      u32 rl = (u + 0x7FFFu + ((u >> 16) & 1u)) >> 16;
      H[j] = (short)rh; M[j] = (short)rm; L[j] = (short)rl;
    }
    u16* basep = pack + ((size_t)(b * 128 + nt) * 12) * 512 + lane * 8;
    *(bf16x8*)(basep + (size_t)(0 + slice) * 512) = H;
    *(bf16x8*)(basep + (size_t)(4 + slice) * 512) = M;
    *(bf16x8*)(basep + (size_t)(8 + slice) * 512) = L;
  }
}

// ---------------- K2: MFMA distances; tau-bound + collect (r7/r11-proven) ----------
// Tau scan kept in FLOAT domain (no orderable-flip: float cmp == key cmp for finite).
#define KNN_LOAD(P, mt) do { const u16* ap_ = pb + (size_t)(mt) * (12*512); \
  P##h0 = *(const bf16x8*)(ap_ + 0*512);  P##h1 = *(const bf16x8*)(ap_ + 1*512); \
  P##h2 = *(const bf16x8*)(ap_ + 2*512);  P##h3 = *(const bf16x8*)(ap_ + 3*512); \
  P##m0 = *(const bf16x8*)(ap_ + 4*512);  P##m1 = *(const bf16x8*)(ap_ + 5*512); \
  P##m2 = *(const bf16x8*)(ap_ + 6*512);  P##m3 = *(const bf16x8*)(ap_ + 7*512); \
  P##l0 = *(const bf16x8*)(ap_ + 8*512);  P##l1 = *(const bf16x8*)(ap_ + 9*512); \
  P##l2 = *(const bf16x8*)(ap_ +10*512);  P##l3 = *(const bf16x8*)(ap_ +11*512); } while(0)

#define SQ_LOAD(MT) do { const float* sp_ = sqb + (MT) * 32 + 4 * h; \
  sv0 = *(const float4*)(sp_);      sv1 = *(const float4*)(sp_ + 8); \
  sv2 = *(const float4*)(sp_ + 16); sv3 = *(const float4*)(sp_ + 24); } while(0)

#define KNN_MFMA(P) \
  acc0 = MFMA32(P##h0, ql0, acc0);  acc1 = MFMA32(P##h1, ql1, acc1); \
  acc0 = MFMA32(P##l0, qh0, acc0);  acc1 = MFMA32(P##l1, qh1, acc1); \
  acc0 = MFMA32(P##m0, qm0, acc0);  acc1 = MFMA32(P##m1, qm1, acc1); \
  acc0 = MFMA32(P##h0, qm0, acc0);  acc1 = MFMA32(P##h1, qm1, acc1); \
  acc0 = MFMA32(P##m0, qh0, acc0);  acc1 = MFMA32(P##m1, qh1, acc1); \
  acc0 = MFMA32(P##h0, qh0, acc0);  acc1 = MFMA32(P##h1, qh1, acc1); \
  acc0 = MFMA32(P##h2, ql2, acc0);  acc1 = MFMA32(P##h3, ql3, acc1); \
  acc0 = MFMA32(P##l2, qh2, acc0);  acc1 = MFMA32(P##l3, qh3, acc1); \
  acc0 = MFMA32(P##m2, qm2, acc0);  acc1 = MFMA32(P##m3, qm3, acc1); \
  acc0 = MFMA32(P##h2, qm2, acc0);  acc1 = MFMA32(P##h3, qm3, acc1); \
  acc0 = MFMA32(P##m2, qh2, acc0);  acc1 = MFMA32(P##m3, qh3, acc1); \
  acc0 = MFMA32(P##h2, qh2, acc0);  acc1 = MFMA32(P##h3, qh3, acc1);

// Loop1 select: direct sorted insert-8, FLOAT keys (same order as flipped-u32)
#define SEL_T8() do { \
  float sqv_[16] = {sv0.x, sv0.y, sv0.z, sv0.w, sv1.x, sv1.y, sv1.z, sv1.w, \
                    sv2.x, sv2.y, sv2.z, sv2.w, sv3.x, sv3.y, sv3.z, sv3.w}; \
_Pragma("unroll") \
  for (int r_ = 0; r_ < 16; ++r_) { \
    float d_ = fmaf(-2.f, acc0[r_] + acc1[r_], sqv_[r_]); \
    if (d_ < kv1[7]) { \
_Pragma("unroll") \
      for (int j_ = 7; j_ > 0; --j_) { \
        float a_ = kv1[j_-1], b_ = kv1[j_]; \
        kv1[j_] = (d_ < a_) ? a_ : ((d_ < b_) ? d_ : b_); \
      } \
      kv1[0] = (d_ < kv1[0]) ? d_ : kv1[0]; \
    } \
  } \
} while(0)

// Loop2 select: float cmp vs tau; flip+pack in push body; batched drain vote per tile
#define SEL_C(MT) do { \
  const u32 ic_ = (u32)((MT) * 32 + 4 * h); \
  float sqv_[16] = {sv0.x, sv0.y, sv0.z, sv0.w, sv1.x, sv1.y, sv1.z, sv1.w, \
                    sv2.x, sv2.y, sv2.z, sv2.w, sv3.x, sv3.y, sv3.z, sv3.w}; \
_Pragma("unroll") \
  for (int r_ = 0; r_ < 16; ++r_) { \
    float d_ = fmaf(-2.f, acc0[r_] + acc1[r_], sqv_[r_]); \
    if (d_ <= tauF) { \
      u32 u_ = __float_as_uint(d_); \
      u_ ^= ((int)u_ < 0) ? 0xFFFFFFFFu : 0x80000000u; \
      myc[cnt] = ((u64)u_ << 32) | (u64)(ic_ + (u32)((r_ & 3) + 8 * (r_ >> 2))); \
      ++cnt; \
    } \
  } \
  if (__any(cnt >= CAPB_ - 16)) {            /* capacity: <=16 adds/tile, cap 33 */ \
    for (int i_ = 0; i_ < cnt; ++i_) insert16(kv, myc[i_]); \
    cnt = 0; \
  } \
} while(0)

__global__ __launch_bounds__(256, 2) void k_knn(const u16* __restrict__ pack,
                                                const float* __restrict__ sq,
                                                u32* __restrict__ kd,
                                                u16* __restrict__ ki,
                                                float* __restrict__ bn_acc) {
  __shared__ u64 cand[256 * CAPB_];          // 67.6 KB: per-lane candidate lists
  const int bx = blockIdx.x;
  const int tid = threadIdx.x;
  if (bx == 0 && tid < 128) bn_acc[tid] = 0.f;   // OFF_BN region untouched elsewhere
  const int split = bx & 1;
  const int qb = (bx >> 1) & 31;
  const int b = bx >> 6;
  const int lane = tid & 63;
  const int wid = tid >> 6;
  const int qt = qb * 4 + wid;               // query tile 0..127
  const int h = lane >> 5;
  const u16* pb = pack + (size_t)b * (128 * 12 * 512) + lane * 8;

  const u16* qp = pb + (size_t)qt * (12 * 512);
  bf16x8 qh0 = *(const bf16x8*)(qp + 0*512), qh1 = *(const bf16x8*)(qp + 1*512);
  bf16x8 qh2 = *(const bf16x8*)(qp + 2*512), qh3 = *(const bf16x8*)(qp + 3*512);
  bf16x8 qm0 = *(const bf16x8*)(qp + 4*512), qm1 = *(const bf16x8*)(qp + 5*512);
  bf16x8 qm2 = *(const bf16x8*)(qp + 6*512), qm3 = *(const bf16x8*)(qp + 7*512);
  bf16x8 ql0 = *(const bf16x8*)(qp + 8*512), ql1 = *(const bf16x8*)(qp + 9*512);
  bf16x8 ql2 = *(const bf16x8*)(qp + 10*512), ql3 = *(const bf16x8*)(qp + 11*512);

  const float* sqb = sq + b * N_;
  const int mbase = split * 64;

  bf16x8 Ah0, Ah1, Ah2, Ah3, Am0, Am1, Am2, Am3, Al0, Al1, Al2, Al3;
  bf16x8 Bh0, Bh1, Bh2, Bh3, Bm0, Bm1, Bm2, Bm3, Bl0, Bl1, Bl2, Bl3;
  float4 sv0, sv1, sv2, sv3;

  // ================= LOOP 1: tau bound from 8 tiles (top-8/lane, float) =========
  float kv1[8];
#pragma unroll
  for (int j = 0; j < 8; ++j) kv1[j] = __uint_as_float(0x7F800000u);  // +INF

  KNN_LOAD(A, mbase);
  for (int ct = 0; ct < TAU_TILES_; ct += 2) {
    SQ_LOAD(mbase + ct);
    KNN_LOAD(B, mbase + ct + 1);
    {
      f32x16 acc0 = {0,0,0,0,0,0,0,0,0,0,0,0,0,0,0,0};
      f32x16 acc1 = {0,0,0,0,0,0,0,0,0,0,0,0,0,0,0,0};
      KNN_MFMA(A)
      SEL_T8();
    }
    SQ_LOAD(mbase + ct + 1);
    KNN_LOAD(A, mbase + ct + 2);                       // tile 8 prefetch: valid mem
    {
      f32x16 acc0 = {0,0,0,0,0,0,0,0,0,0,0,0,0,0,0,0};
      f32x16 acc1 = {0,0,0,0,0,0,0,0,0,0,0,0,0,0,0,0};
      KNN_MFMA(B)
      SEL_T8();
    }
  }
  float tkF = kv1[7];
  float pkF = __shfl_xor(tkF, 32);
  const float tauF = (tkF > pkF) ? tkF : pkF;  // >= exact 16th-smallest of the split

  // ================= LOOP 2: collect d <= tau over all 64 tiles =================
  u64 kv[16];
#pragma unroll
  for (int j = 0; j < 16; ++j) kv[j] = 0xFF8000000000FFFFull;
  int cnt = 0;
  u64* myc = cand + tid * CAPB_;

  KNN_LOAD(A, mbase);
  for (int ct = 0; ct < 64; ct += 2) {
    SQ_LOAD(mbase + ct);
    KNN_LOAD(B, mbase + ct + 1);
    {
      f32x16 acc0 = {0,0,0,0,0,0,0,0,0,0,0,0,0,0,0,0};
      f32x16 acc1 = {0,0,0,0,0,0,0,0,0,0,0,0,0,0,0,0};
      KNN_MFMA(A)
      SEL_C(mbase + ct);
    }
    SQ_LOAD(mbase + ct + 1);
    KNN_LOAD(A, mbase + ((ct + 2) & 63));
    {
      f32x16 acc0 = {0,0,0,0,0,0,0,0,0,0,0,0,0,0,0,0};
      f32x16 acc1 = {0,0,0,0,0,0,0,0,0,0,0,0,0,0,0,0};
      KNN_MFMA(B)
      SEL_C(mbase + ct + 1);
    }
  }
  for (int i = 0; i < cnt; ++i) insert16(kv, myc[i]);  // final drain

  // merge lane halves (half-cleaner -> bitonic), then bitonic-merge sort
  u64 m[16];
#pragma unroll
  for (int j = 0; j < 16; ++j) {
    u64 p = __shfl_xor(kv[15 - j], 32);
    m[j] = (kv[j] < p) ? kv[j] : p;
  }
#pragma unroll
  for (int d = 8; d >= 1; d >>= 1) {
#pragma unroll
    for (int j = 0; j < 16; ++j) {
      if ((j & d) == 0) {
        u64 a = m[j], c = m[j | d];
        m[j] = (a < c) ? a : c;
        m[j | d] = (a < c) ? c : a;
      }
    }
  }

  if (lane < 32) {
    const int row = b * N_ + qt * 32 + lane;
    u32* dp = kd + ((size_t)row * NSPLIT_ + split) * 16;
    u16* ip = ki + ((size_t)row * NSPLIT_ + split) * 16;
#pragma unroll
    for (int j = 0; j < 16; ++j) {
      dp[j] = (u32)(m[j] >> 32);
      ip[j] = (u16)(m[j] & 0xFFFFu);
    }
  }
}

// ---------------- K3: fused merge + GIN aggregation + GEMM1 + BN partial sums ----
// block = 16 rows, 256 threads, 2048 blocks. phase1 gathers with float4: quarter-wave
// per row (lane = (rowgrp, ch/4)), 4 rows concurrent, 4x fewer load instructions.
__global__ __launch_bounds__(256) void k_mid(const u32* __restrict__ kd,
                                             const u16* __restrict__ ki,
                                             const float* __restrict__ xf,
                                             const float* __restrict__ eps_gin,
                                             const float* __restrict__ w1,
                                             const float* __restrict__ b1,
                                             float* __restrict__ h1,
                                             float* __restrict__ bn_acc) {
  __shared__ float wT[64 * 65];                 // w1 transposed: wT[o][c] (16.6 KB)
  __shared__ float hL[MIDROWS_ * 68];           // aggregated rows, float4-aligned stride
  __shared__ int   knnL[MIDROWS_ * 16];
  __shared__ float rs[4][64], rs2[4][64];
  const int tid = threadIdx.x;
  const int r0 = blockIdx.x * MIDROWS_;
#pragma unroll
  for (int i = 0; i < 16; ++i) {
    int idx = tid + i * 256;                    // w1[c][o], idx = c*64+o
    wT[(idx & 63) * 65 + (idx >> 6)] = w1[idx];
  }
  {
    const int row = tid >> 4;                   // 16 rows x 16 j = 256 threads
    const int j = tid & 15;
    const u32* dp = kd + (size_t)(r0 + row) * (NSPLIT_ * 16);
    const u16* ip = ki + (size_t)(r0 + row) * (NSPLIT_ * 16);
    u64 a = ((u64)dp[j] << 32) | ip[j];
    u64 bb = ((u64)dp[16 + (15 - j)] << 32) | ip[16 + (15 - j)];
    knnL[row * 16 + j] = (int)((a < bb ? a : bb) & 0xFFFFu);  // set semantics
  }
  __syncthreads();
  const int q = tid >> 6;
  const int b = r0 >> 12;
  const float* xfb = xf + (size_t)b * N_ * 64;
  const float eps1 = 1.f + eps_gin[0];
  {
    const int lane = tid & 63;
    const int rg = lane >> 4;                   // row within wave's group of 4
    const int ch = (lane & 15) * 4;             // channel block
    const int rl = q * 4 + rg;                  // local row 0..15
    float4 v = *(const float4*)&xfb[(size_t)((r0 & (N_ - 1)) + rl) * 64 + ch];
    v.x *= eps1; v.y *= eps1; v.z *= eps1; v.w *= eps1;
    const int* kn = knnL + rl * 16;
#pragma unroll
    for (int j = 0; j < 16; ++j) {
      int mr = kn[j];                           // quarter-wave-uniform LDS read
      float4 g = *(const float4*)&xfb[(size_t)mr * 64 + ch];  // 16B gather
      v.x += g.x; v.y += g.y; v.z += g.z; v.w += g.w;         // same per-ch order
    }
    *(float4*)&hL[rl * 68 + ch] = v;            // aligned; banks 2-way (free)
  }
  __syncthreads();
  const int o = tid & 63;
  const float bias = b1[o];
  float s = 0.f, s2 = 0.f;
#pragma unroll
  for (int i = 0; i < 4; ++i) {
    int rl = q * 4 + i;
    float acc = bias;
#pragma unroll
    for (int k = 0; k < 16; ++k) {
      float4 hv = *(const float4*)&hL[rl * 68 + 4 * k];   // uniform -> broadcast
      float4 wv = *(const float4*)&wT[o * 65 + 4 * k];    // pad-65: conflict-free
      acc += hv.x * wv.x; acc += hv.y * wv.y;             // ascending c: same order
      acc += hv.z * wv.z; acc += hv.w * wv.w;             //  as previous kernel
    }
    h1[(size_t)(r0 + rl) * 64 + o] = acc;
    s += acc; s2 += acc * acc;
  }
  rs[q][o] = s; rs2[q][o] = s2;
  __syncthreads();
  if (tid < 64) {
    float ts  = rs[0][tid] + rs[1][tid] + rs[2][tid] + rs[3][tid];
    float ts2 = rs2[0][tid] + rs2[1][tid] + rs2[2][tid] + rs2[3][tid];
    atomicAdd(&bn_acc[tid], ts);
    atomicAdd(&bn_acc[64 + tid], ts2);
  }
}

// ---------------- K4: BN finalize + apply + GELU(erf) + GEMM2 + transposed store ----
__global__ __launch_bounds__(256) void k_final(const float* __restrict__ h1,
                                               const float* __restrict__ bn_acc,
                                               const float* __restrict__ gamma,
                                               const float* __restrict__ beta,
                                               const float* __restrict__ w2,
                                               const float* __restrict__ b2,
                                               float* __restrict__ out) {
  __shared__ float wT2[64 * 65];                // w2 transposed: wT2[o2][oo] (16.6 KB)
  __shared__ float hg[FINROWS_ * 65];           // 8.3 KB, padded
  __shared__ float scsh[128];
  const int tid = threadIdx.x;
#pragma unroll
  for (int i = 0; i < 16; ++i) {
    int idx = tid + i * 256;                    // w2[oo][o2], idx = oo*64+o2
    wT2[(idx & 63) * 65 + (idx >> 6)] = w2[idx];
  }
  if (tid < 64) {                               // fused BN finalize (per-block recompute)
    const float inv = 1.f / (float)ROWS_;
    float mean = bn_acc[tid] * inv;
    float var  = bn_acc[64 + tid] * inv - mean * mean;
    float sc = gamma[tid] * rsqrtf(var + 1e-5f);
    scsh[tid] = sc;
    scsh[64 + tid] = beta[tid] - mean * sc;
  }
  __syncthreads();
  const int r0 = blockIdx.x * FINROWS_;
  const int b  = r0 >> 12;
  const int n0 = r0 & (N_ - 1);
  const int o = tid & 63;
  const int q = tid >> 6;
  const float sc = scsh[o], sh = scsh[64 + o];
#pragma unroll
  for (int i = 0; i < 8; ++i) {
    int rl = q + i * 4;                         // rows 0..31
    float v = h1[(size_t)(r0 + rl) * 64 + o] * sc + sh;
    float g = 0.5f * v * (1.f + erff(v * 0.70710678118654752f));
    hg[rl * 65 + o] = g;
  }
  __syncthreads();
  const int nl = tid & 31;
  const int g8 = tid >> 5;                      // 8 o2-groups
  float4 hv[16];                                // hoist own hg row (64 VGPR)
#pragma unroll
  for (int k = 0; k < 16; ++k) hv[k] = *(const float4*)&hg[nl * 65 + 4 * k];
#pragma unroll
  for (int i = 0; i < 8; ++i) {
    int o2 = g8 * 8 + i;                        // half-wave-uniform
    float acc = b2[o2];
#pragma unroll
    for (int k = 0; k < 16; ++k) {
      float4 wv = *(const float4*)&wT2[o2 * 65 + 4 * k];  // broadcast per half-wave
      acc += hv[k].x * wv.x; acc += hv[k].y * wv.y;       // ascending oo: same
      acc += hv[k].z * wv.z; acc += hv[k].w * wv.w;       //  order as before
    }
    out[((size_t)(b * 64 + o2)) * N_ + n0 + nl] = acc;    // 128B segments over n
  }
}

extern "C" void kernel_launch(void* const* d_in, const int* in_sizes, int n_in,
                              void* d_out, int out_size, void* d_ws, size_t ws_size,
                              hipStream_t stream) {
  const float* x     = (const float*)d_in[0];
  const float* w1    = (const float*)d_in[1];
  const float* b1    = (const float*)d_in[2];
  const float* gamma = (const float*)d_in[3];
  const float* beta  = (const float*)d_in[4];
  const float* w2    = (const float*)d_in[5];
  const float* b2    = (const float*)d_in[6];
  const float* eps_g = (const float*)d_in[7];
  float* out = (float*)d_out;

  char* ws = (char*)d_ws;
  float* xf   = (float*)(ws + OFF_XF);
  float* sq   = (float*)(ws + OFF_SQ);
  u32*   kd   = (u32*)  (ws + OFF_KD);
  u16*   ki   = (u16*)  (ws + OFF_KI);
  u16*   pack = (u16*)  (ws + OFF_PACK);
  float* h1   = (float*)(ws + OFF_H1);         // aliases pack head (dead after knn)
  float* bn_acc = (float*)(ws + OFF_BN);       // own region; zeroed by k_knn blk 0

  k_transpose<<<1024, 256, 0, stream>>>(x, xf, sq, pack);
  k_knn<<<512, 256, 0, stream>>>(pack, sq, kd, ki, bn_acc);
  k_mid<<<ROWS_ / MIDROWS_, 256, 0, stream>>>(kd, ki, xf, eps_g, w1, b1, h1, bn_acc);
  k_final<<<ROWS_ / FINROWS_, 256, 0, stream>>>(h1, bn_acc, gamma, beta, w2, b2, out);
}